// Round 1
// baseline (435.612 us; speedup 1.0000x reference)
//
#include <hip/hip_runtime.h>
#include <math.h>

// Problem constants: B=32768, L=2, D=1024, DK=1
constexpr int D_DIM = 1024;
constexpr float INV_SQRT_D = 0.03125f;  // 1/sqrt(1024)

typedef float f32x4 __attribute__((ext_vector_type(4)));

// One wave (64 lanes) per TWO batch elements.
// lane l owns float4 chunks {l, l+64, l+128, l+192} of each 1024-float row.
// Processing 2 batches per wave amortizes the butterfly-reduce bubble and the
// (L1-hit) W reload across 2x the HBM bytes, keeping the VMEM pipe busier.
__global__ __launch_bounds__(256, 4) void attn_collapse_kernel(
    const float* __restrict__ X,   // (B, 2, D)
    const float* __restrict__ W,   // (D,) since DK=1
    float* __restrict__ Y,         // (B, 2, D)
    int B) {
  const int gthread = blockIdx.x * blockDim.x + threadIdx.x;
  const int wave = gthread >> 6;
  const int lane = threadIdx.x & 63;
  const int bA = wave << 1;            // this wave handles batches bA, bA+1
  if (bA >= B) return;
  const bool hasB = (bA + 1) < B;

  const float* A0 = X + (size_t)bA * (2 * D_DIM);
  const float* A1 = A0 + D_DIM;
  // If no second batch (odd tail), alias back to A0 so loads stay in-bounds;
  // results are discarded by the guarded store.
  const float* B0 = hasB ? (A1 + D_DIM) : A0;
  const float* B1 = B0 + D_DIM;

  f32x4 xa0[4], xa1[4], xb0[4], xb1[4], wv[4];

  // Issue all 20 dwordx4 loads up front (320 B/lane in flight).
#pragma unroll
  for (int k = 0; k < 4; ++k) {
    const int idx = (lane + (k << 6)) << 2;  // float offset, 16B-aligned
    wv[k]  = *(const f32x4*)(W + idx);
    xa0[k] = *(const f32x4*)(A0 + idx);
    xa1[k] = *(const f32x4*)(A1 + idx);
    xb0[k] = *(const f32x4*)(B0 + idx);
    xb1[k] = *(const f32x4*)(B1 + idx);
  }

  float da0 = 0.f, da1 = 0.f, db0 = 0.f, db1 = 0.f, ws = 0.f;
#pragma unroll
  for (int k = 0; k < 4; ++k) {
#pragma unroll
    for (int j = 0; j < 4; ++j) {
      const float w = wv[k][j];
      da0 += xa0[k][j] * w;
      da1 += xa1[k][j] * w;
      db0 += xb0[k][j] * w;
      db1 += xb1[k][j] * w;
      ws  += w;
    }
  }

  // Single 6-level butterfly over 5 independent chains (they pipeline).
#pragma unroll
  for (int off = 32; off > 0; off >>= 1) {
    da0 += __shfl_xor(da0, off, 64);
    da1 += __shfl_xor(da1, off, 64);
    db0 += __shfl_xor(db0, off, 64);
    db1 += __shfl_xor(db1, off, 64);
    ws  += __shfl_xor(ws, off, 64);
  }

  const float wsI = ws * INV_SQRT_D;

  // Batch A: q0 = (d0 + ws/32)/32 ; q1 = (d1 - ws/32)/32
  const float qa0 = (da0 + wsI) * INV_SQRT_D;
  const float qa1 = (da1 - wsI) * INV_SQRT_D;
  const float dqa = qa0 - qa1;
  const float aA00 = 1.f / (1.f + __expf(-(qa0 * dqa)));
  const float aA10 = 1.f / (1.f + __expf(-(qa1 * dqa)));
  const float bA00 = 1.f - aA00;
  const float bA10 = 1.f - aA10;

  // Batch B
  const float qb0 = (db0 + wsI) * INV_SQRT_D;
  const float qb1 = (db1 - wsI) * INV_SQRT_D;
  const float dqb = qb0 - qb1;
  const float aB00 = 1.f / (1.f + __expf(-(qb0 * dqb)));
  const float aB10 = 1.f / (1.f + __expf(-(qb1 * dqb)));
  const float bB00 = 1.f - aB00;
  const float bB10 = 1.f - aB10;

  float* yA0 = Y + (size_t)bA * (2 * D_DIM);
  float* yA1 = yA0 + D_DIM;
  float* yB0 = yA1 + D_DIM;
  float* yB1 = yB0 + D_DIM;

#pragma unroll
  for (int k = 0; k < 4; ++k) {
    const int idx = (lane + (k << 6)) << 2;

    f32x4 p0, p1, o0, o1;
#pragma unroll
    for (int j = 0; j < 4; ++j) {
      p0[j] = xa0[k][j] + INV_SQRT_D;   // row0 positional +1/32
      p1[j] = xa1[k][j] - INV_SQRT_D;   // row1 positional -1/32
      o0[j] = aA00 * p0[j] + bA00 * p1[j];
      o1[j] = aA10 * p0[j] + bA10 * p1[j];
    }
    *(f32x4*)(yA0 + idx) = o0;
    *(f32x4*)(yA1 + idx) = o1;

    if (hasB) {
#pragma unroll
      for (int j = 0; j < 4; ++j) {
        p0[j] = xb0[k][j] + INV_SQRT_D;
        p1[j] = xb1[k][j] - INV_SQRT_D;
        o0[j] = aB00 * p0[j] + bB00 * p1[j];
        o1[j] = aB10 * p0[j] + bB10 * p1[j];
      }
      *(f32x4*)(yB0 + idx) = o0;
      *(f32x4*)(yB1 + idx) = o1;
    }
  }
}

extern "C" void kernel_launch(void* const* d_in, const int* in_sizes, int n_in,
                              void* d_out, int out_size, void* d_ws, size_t ws_size,
                              hipStream_t stream) {
  const float* X = (const float*)d_in[0];
  const float* W = (const float*)d_in[1];
  float* Y = (float*)d_out;

  const int B = in_sizes[0] / (2 * D_DIM);  // 32768

  // 2 batches per wave, 4 waves per block -> 8 batches per block.
  const int blocks = (B + 7) / 8;
  attn_collapse_kernel<<<blocks, 256, 0, stream>>>(X, W, Y, B);
}

// Round 2
// 425.678 us; speedup vs baseline: 1.0233x; 1.0233x over previous
//
#include <hip/hip_runtime.h>
#include <math.h>

// Problem constants: B=32768, L=2, D=1024, DK=1
constexpr int D_DIM = 1024;
constexpr float INV_SQRT_D = 0.03125f;  // 1/sqrt(1024)

typedef float f32x4 __attribute__((ext_vector_type(4)));

// One wave (64 lanes) per batch element.
// lane l owns float4 chunks {l, l+64, l+128, l+192} of each 1024-float row.
//
// Algebra: R-row offsets folded into the load phase:
//   p0 = x0 + 1/32, p1 = x1 - 1/32  (these are the X_pos rows, reused in the
//   epilogue), and q0 = dot(p0, W)/32, q1 = dot(p1, W)/32 — which removes the
//   separate sum(W) accumulator and its butterfly chain (3 chains -> 2).
__global__ __launch_bounds__(256) void attn_collapse_kernel(
    const float* __restrict__ X,   // (B, 2, D)
    const float* __restrict__ W,   // (D,) since DK=1
    float* __restrict__ Y,         // (B, 2, D)
    int B) {
  const int gthread = blockIdx.x * blockDim.x + threadIdx.x;
  const int wave = gthread >> 6;
  const int lane = threadIdx.x & 63;
  if (wave >= B) return;

  const float* x0base = X + (size_t)wave * (2 * D_DIM);
  const float* x1base = x0base + D_DIM;

  f32x4 p0[4], p1[4];
  float d0 = 0.f, d1 = 0.f;

#pragma unroll
  for (int k = 0; k < 4; ++k) {
    const int idx = (lane + (k << 6)) << 2;  // float offset, 16B-aligned
    const f32x4 w = *(const f32x4*)(W + idx);
    const f32x4 a = *(const f32x4*)(x0base + idx);
    const f32x4 b = *(const f32x4*)(x1base + idx);
#pragma unroll
    for (int j = 0; j < 4; ++j) {
      p0[k][j] = a[j] + INV_SQRT_D;   // X_pos row 0
      p1[k][j] = b[j] - INV_SQRT_D;   // X_pos row 1
      d0 += p0[k][j] * w[j];
      d1 += p1[k][j] * w[j];
    }
  }

  // Butterfly reduce across the 64-lane wave (2 independent chains).
#pragma unroll
  for (int off = 32; off > 0; off >>= 1) {
    d0 += __shfl_xor(d0, off, 64);
    d1 += __shfl_xor(d1, off, 64);
  }

  const float q0 = d0 * INV_SQRT_D;
  const float q1 = d1 * INV_SQRT_D;
  const float dq = q0 - q1;
  // softmax of [[q0q0, q0q1],[q1q0, q1q1]] rows -> sigmoids of row-diffs
  const float a00 = 1.f / (1.f + __expf(-(q0 * dq)));
  const float a10 = 1.f / (1.f + __expf(-(q1 * dq)));

  float* y0 = Y + (size_t)wave * (2 * D_DIM);
  float* y1 = y0 + D_DIM;

#pragma unroll
  for (int k = 0; k < 4; ++k) {
    const int idx = (lane + (k << 6)) << 2;
    f32x4 o0, o1;
#pragma unroll
    for (int j = 0; j < 4; ++j) {
      const float dif = p0[k][j] - p1[k][j];
      o0[j] = p1[k][j] + a00 * dif;    // a00*p0 + (1-a00)*p1
      o1[j] = p1[k][j] + a10 * dif;    // a10*p0 + (1-a10)*p1
    }
    *(f32x4*)(y0 + idx) = o0;
    *(f32x4*)(y1 + idx) = o1;
  }
}

extern "C" void kernel_launch(void* const* d_in, const int* in_sizes, int n_in,
                              void* d_out, int out_size, void* d_ws, size_t ws_size,
                              hipStream_t stream) {
  const float* X = (const float*)d_in[0];
  const float* W = (const float*)d_in[1];
  float* Y = (float*)d_out;

  const int B = in_sizes[0] / (2 * D_DIM);  // 32768

  const int waves_per_block = 4;            // 256 threads
  const int blocks = (B + waves_per_block - 1) / waves_per_block;
  attn_collapse_kernel<<<blocks, 256, 0, stream>>>(X, W, Y, B);
}